// Round 1
// baseline (185.440 us; speedup 1.0000x reference)
//
#include <hip/hip_runtime.h>
#include <hip/hip_bf16.h>

#define TT 64
#define DD 255
#define KK 256
#define MM 512
#define CC 8
#define BB 4096
#define NB 4

// ---------------- kernel 0: extract feature index from one-hot W1 ----------
__global__ void feat_kernel(const float* __restrict__ W1, int* __restrict__ feat) {
    int idx = blockIdx.x * 256 + threadIdx.x;
    if (idx >= TT * DD) return;
    const float4* row = reinterpret_cast<const float4*>(W1 + (size_t)idx * MM);
    float acc = 0.0f;
    #pragma unroll 4
    for (int m4 = 0; m4 < MM / 4; ++m4) {
        float4 w = row[m4];
        float base = (float)(4 * m4);
        acc = fmaf(w.x, base,          acc);
        acc = fmaf(w.y, base + 1.0f,   acc);
        acc = fmaf(w.z, base + 2.0f,   acc);
        acc = fmaf(w.w, base + 3.0f,   acc);
    }
    feat[idx] = (int)(acc + 0.5f);
}

// s = sigmoid(10*(xv+b)) = 1/(1+2^(-10*log2(e)*(xv+b))); c1 = -14.4269504*b
__device__ __forceinline__ float sigm_from(float xv, float c1) {
    float earg = fmaf(-14.426950408889634f, xv, c1);
    float e = exp2f(earg);                 // native v_exp_f32
    return __builtin_amdgcn_rcpf(1.0f + e);
}

__device__ __forceinline__ float wave_sum(float v) {
    v += __shfl_down(v, 32, 64);
    v += __shfl_down(v, 16, 64);
    v += __shfl_down(v, 8, 64);
    v += __shfl_down(v, 4, 64);
    v += __shfl_down(v, 2, 64);
    v += __shfl_down(v, 1, 64);
    return v;
}

#define FMA4(acc, s, v)                         \
    do {                                        \
        (acc).x = fmaf((s), (v).x, (acc).x);    \
        (acc).y = fmaf((s), (v).y, (acc).y);    \
        (acc).z = fmaf((s), (v).z, (acc).z);    \
        (acc).w = fmaf((s), (v).w, (acc).w);    \
    } while (0)

// ---------------- kernel 1: forest forward -------------------------------
// block: 256 threads = (pair i in [0,128), sub in {0,1}); NB=4 batch rows.
// 8 passes x 8 trees; s8 layout [bl][sub][node][4 trees], node stride 16B.
__global__ __launch_bounds__(256, 2) void forest_kernel(
        const float* __restrict__ x, const float* __restrict__ b1,
        const float* __restrict__ Cw, const int* __restrict__ feat,
        float* __restrict__ out) {
    __shared__ float xsi[MM][NB];           // 8 KB   [m][bl]
    __shared__ float s8[NB * 2 * 256 * 4];  // 32 KB  [bl][sub][node][j]
    __shared__ float4 red4[4][NB][2];       // 512 B

    const int tid = threadIdx.x;
    const int b0 = blockIdx.x * NB;

    // stage x rows, interleaved so a gather b128 read serves all 4 rows
    for (int idx = tid; idx < MM * NB; idx += 256) {
        int m = idx & (MM - 1);
        int bl = idx >> 9;
        xsi[m][bl] = x[(size_t)(b0 + bl) * MM + m];
    }

    float4 accA[NB], accB[NB];
    #pragma unroll
    for (int bl = 0; bl < NB; ++bl) {
        accA[bl] = make_float4(0.f, 0.f, 0.f, 0.f);
        accB[bl] = make_float4(0.f, 0.f, 0.f, 0.f);
    }

    const int i = tid & 127;   // leaf pair: leaves 2i, 2i+1
    const int sub = tid >> 7;  // which 4-tree subgroup of the pass

    for (int g = 0; g < 8; ++g) {
        __syncthreads();
        // ---- stage sigmoids for 8 trees x 4 batch rows ----
        if (tid < DD) {
            const int d = tid;
            int f[8];
            float c1[8];
            #pragma unroll
            for (int j = 0; j < 8; ++j) {
                int t = g * 8 + j;
                f[j] = feat[t * DD + d];
                c1[j] = -14.426950408889634f * b1[t * DD + d];
            }
            float sv[NB][8];
            #pragma unroll
            for (int j = 0; j < 8; ++j) {
                float4 xv = *reinterpret_cast<const float4*>(&xsi[f[j]][0]);
                sv[0][j] = sigm_from(xv.x, c1[j]);
                sv[1][j] = sigm_from(xv.y, c1[j]);
                sv[2][j] = sigm_from(xv.z, c1[j]);
                sv[3][j] = sigm_from(xv.w, c1[j]);
            }
            #pragma unroll
            for (int bl = 0; bl < NB; ++bl) {
                float* p0 = &s8[(bl * 2 + 0) * 1024 + d * 4];
                float* p1 = &s8[(bl * 2 + 1) * 1024 + d * 4];
                *reinterpret_cast<float4*>(p0) =
                    make_float4(sv[bl][0], sv[bl][1], sv[bl][2], sv[bl][3]);
                *reinterpret_cast<float4*>(p1) =
                    make_float4(sv[bl][4], sv[bl][5], sv[bl][6], sv[bl][7]);
            }
        }
        __syncthreads();

        // ---- register-cache Cw for my 2 leaves x 4 trees (reused over 4 b) ----
        float4 cA0[4], cA1[4], cB0[4], cB1[4];
        #pragma unroll
        for (int j = 0; j < 4; ++j) {
            int t = g * 8 + sub * 4 + j;
            const float4* p = reinterpret_cast<const float4*>(
                Cw + ((size_t)t * KK + 2 * i) * CC);
            cA0[j] = p[0];  // leaf 2i,   c0..3
            cA1[j] = p[1];  // leaf 2i,   c4..7
            cB0[j] = p[2];  // leaf 2i+1, c0..3
            cB1[j] = p[3];  // leaf 2i+1, c4..7
        }

        // ---- path product, 4 batch rows in parallel ----
        const float* sbase = &s8[sub * 1024];
        float4 pre[NB];
        #pragma unroll
        for (int bl = 0; bl < NB; ++bl) pre[bl] = make_float4(1.f, 1.f, 1.f, 1.f);

        #pragma unroll
        for (int lev = 0; lev < 7; ++lev) {
            int node = (1 << lev) - 1 + (i >> (7 - lev));
            int bit = (i >> (6 - lev)) & 1;
            float offv = 1.0f - (float)bit;
            float sg = 2.0f * (float)bit - 1.0f;   // bit? s : 1-s == fma(sg,s,offv)
            const float* sp = sbase + node * 4;
            #pragma unroll
            for (int bl = 0; bl < NB; ++bl) {
                float4 s = *reinterpret_cast<const float4*>(sp + bl * 2048);
                pre[bl].x *= fmaf(sg, s.x, offv);
                pre[bl].y *= fmaf(sg, s.y, offv);
                pre[bl].z *= fmaf(sg, s.z, offv);
                pre[bl].w *= fmaf(sg, s.w, offv);
            }
        }
        const float* sp7 = sbase + (127 + i) * 4;
        #pragma unroll
        for (int bl = 0; bl < NB; ++bl) {
            float4 s7 = *reinterpret_cast<const float4*>(sp7 + bl * 2048);
            float4 pe, po;
            pe.x = pre[bl].x * (1.0f - s7.x);  po.x = pre[bl].x * s7.x;
            pe.y = pre[bl].y * (1.0f - s7.y);  po.y = pre[bl].y * s7.y;
            pe.z = pre[bl].z * (1.0f - s7.z);  po.z = pre[bl].z * s7.z;
            pe.w = pre[bl].w * (1.0f - s7.w);  po.w = pre[bl].w * s7.w;
            float pear[4] = {pe.x, pe.y, pe.z, pe.w};
            float poar[4] = {po.x, po.y, po.z, po.w};
            #pragma unroll
            for (int j = 0; j < 4; ++j) {
                FMA4(accA[bl], pear[j], cA0[j]);
                FMA4(accB[bl], pear[j], cA1[j]);
                FMA4(accA[bl], poar[j], cB0[j]);
                FMA4(accB[bl], poar[j], cB1[j]);
            }
        }
    }

    // ---- block reduction: 32 partial sums (4 b x 8 classes) ----
    const int lane = tid & 63;
    const int wv = tid >> 6;
    #pragma unroll
    for (int bl = 0; bl < NB; ++bl) {
        accA[bl].x = wave_sum(accA[bl].x);
        accA[bl].y = wave_sum(accA[bl].y);
        accA[bl].z = wave_sum(accA[bl].z);
        accA[bl].w = wave_sum(accA[bl].w);
        accB[bl].x = wave_sum(accB[bl].x);
        accB[bl].y = wave_sum(accB[bl].y);
        accB[bl].z = wave_sum(accB[bl].z);
        accB[bl].w = wave_sum(accB[bl].w);
    }
    if (lane == 0) {
        #pragma unroll
        for (int bl = 0; bl < NB; ++bl) {
            red4[wv][bl][0] = accA[bl];
            red4[wv][bl][1] = accB[bl];
        }
    }
    __syncthreads();
    if (tid < NB * CC) {
        int bl = tid >> 3;
        int c = tid & 7;
        const float* r0 = reinterpret_cast<const float*>(&red4[0][bl][0]);
        const float* r1 = reinterpret_cast<const float*>(&red4[1][bl][0]);
        const float* r2 = reinterpret_cast<const float*>(&red4[2][bl][0]);
        const float* r3 = reinterpret_cast<const float*>(&red4[3][bl][0]);
        float s = r0[c] + r1[c] + r2[c] + r3[c];
        out[(size_t)(b0 + bl) * CC + c] = s * (1.0f / 64.0f);
    }
}

extern "C" void kernel_launch(void* const* d_in, const int* in_sizes, int n_in,
                              void* d_out, int out_size, void* d_ws, size_t ws_size,
                              hipStream_t stream) {
    const float* x  = (const float*)d_in[0];  // [B, M]
    const float* W1 = (const float*)d_in[1];  // [T, D, M] one-hot rows
    const float* b1 = (const float*)d_in[2];  // [T, D]
    // d_in[3] = Bpos, d_in[4] = Bneg: fixed complete-tree path masks (hardcoded)
    const float* Cw = (const float*)d_in[5];  // [T, K, C]
    float* out = (float*)d_out;               // [B, C] fp32
    int* feat = (int*)d_ws;                   // T*D ints, rebuilt every call

    feat_kernel<<<(TT * DD + 255) / 256, 256, 0, stream>>>(W1, feat);
    forest_kernel<<<BB / NB, 256, 0, stream>>>(x, b1, Cw, feat, out);
}